// Round 18
// baseline (59.417 us; speedup 1.0000x reference)
//
#include <hip/hip_runtime.h>
#include <cmath>

#define N_TOKENS 65536
#define DIM 256
#define NCLUST 128
#define DOUT 256

#define EPS 2e-3f

typedef _Float16 f16_t;
typedef f16_t f16x8 __attribute__((ext_vector_type(8)));
typedef float f32x4 __attribute__((ext_vector_type(4)));
typedef float fvec4 __attribute__((ext_vector_type(4)));

__device__ inline void split2(float x, f16_t& h, f16_t& m) {
    h = (f16_t)x;
    float r = x - (float)h;   // exact (Sterbenz)
    m = (f16_t)r;             // dropped residual ~2^-22 relative
}

__device__ inline void lds_load16(void* lds, const void* g) {
    __builtin_amdgcn_global_load_lds(
        (const __attribute__((address_space(1))) unsigned int*)g,
        (__attribute__((address_space(3))) unsigned int*)lds, 16, 0, 0);
}

// ---------------- kernel 1: precompute (unchanged, 10x-passing) ---------
__global__ __launch_bounds__(256) void precompute_kernel(
    const float* __restrict__ centers,
    const float* __restrict__ proj_w,
    const float* __restrict__ proj_b,
    float* __restrict__ pc,
    float* __restrict__ csq,
    f16_t* __restrict__ cbs)
{
    __shared__ float cl[DIM];
    __shared__ float red[4];
    const int n = blockIdx.x;
    const int tid = threadIdx.x;

    float cv = centers[n * DIM + tid];
    cl[tid] = cv;

    f16_t h, m;
    split2(cv, h, m);
    {
        int s  = tid >> 5;
        int k8 = (tid >> 3) & 3;
        int j  = tid & 7;
        size_t base = (size_t)(s * 128 + n) * 8;
        cbs[(base + ((k8    ) ^ (n & 7))) * 8 + j] = h;   // plane 0 (high)
        cbs[(base + ((4 + k8) ^ (n & 7))) * 8 + j] = m;   // plane 1 (mid)
    }

    float s = cv * cv;
    #pragma unroll
    for (int off = 32; off >= 1; off >>= 1)
        s += __shfl_down(s, off, 64);
    if ((tid & 63) == 0) red[tid >> 6] = s;
    __syncthreads();
    if (tid == 0) csq[n] = (red[0] + red[1]) + (red[2] + red[3]);

    float acc = 0.f;
    const float* wrow = proj_w + (size_t)tid * DIM;
    #pragma unroll 4
    for (int d = 0; d < DIM; d += 4) {
        float4 w = *(const float4*)(wrow + d);
        acc = fmaf(w.x, cl[d + 0], acc);
        acc = fmaf(w.y, cl[d + 1], acc);
        acc = fmaf(w.z, cl[d + 2], acc);
        acc = fmaf(w.w, cl[d + 3], acc);
    }
    pc[(size_t)n * DOUT + tid] = acc + proj_b[tid];
}

// ------- kernel 2: K-split B, barrier-drained ring, roomy reg cap -------
__global__ __launch_bounds__(1024, 4) void cluster_mfma_kernel(
    const float* __restrict__ x,
    const float* __restrict__ centers,
    const f16_t* __restrict__ cbs,
    const float* __restrict__ csq,
    int* __restrict__ best_out)
{
    __shared__ f16_t Bs[NCLUST * 128 * 2];   // 65536 B: one K-half of split-B
    __shared__ float scs[NCLUST];
    __shared__ int sbest[16][16];
    __shared__ int scnt[16][16];

    const int tid = threadIdx.x;
    const int lane = tid & 63;
    const int wid = tid >> 6;               // 0..15
    const int lr = lane & 15;
    const int lg = lane >> 4;
    const int tw = blockIdx.x * 256 + wid * 16;   // this wave's 16 tokens

    // stage one 64 KB K-half of the pre-swizzled B image (4096 x 16B chunks)
    #define STAGE(half) do {                                                 \
        _Pragma("unroll")                                                    \
        for (int it = 0; it < 4; ++it) {                                     \
            int o = it * 1024 + tid;                                         \
            lds_load16((char*)Bs + o * 16,                                   \
                       (const char*)cbs + (half) * 65536 + o * 16);          \
        }                                                                    \
    } while (0)

    // A: token = tw + lr, k = ks*32 + lg*8 + j  (fp32 from global)
    const float* p0 = x + (size_t)(tw + lr) * DIM + lg * 8;

    // 4-slot ASM ring, 2 dwordx4 per slot. volatile asm: cannot be sunk.
    // EVERY slot is issued in the gap before a __syncthreads and consumed
    // after it: the barrier's compiler-emitted vmcnt(0) (forced by the
    // tracked STAGE loads) drains them. No counted vmcnt; each ax live
    // range spans exactly ONE barrier. Roomy (1024,4) cap => no spills of
    // async asm outputs (the r17 corruption mechanism).
    fvec4 ax[4][2];
    #define AISSUE(slot, ksv) do {                                           \
        asm volatile("global_load_dwordx4 %0, %1, off offset:%c2"            \
                     : "=&v"(ax[slot][0]) : "v"(p0), "i"((ksv) * 128)        \
                     : "memory");                                            \
        asm volatile("global_load_dwordx4 %0, %1, off offset:%c2"            \
                     : "=&v"(ax[slot][1]) : "v"(p0), "i"((ksv) * 128 + 16)   \
                     : "memory");                                            \
    } while (0)

    STAGE(0);
    AISSUE(0, 0);
    AISSUE(1, 1);
    AISSUE(2, 2);
    AISSUE(3, 3);
    if (tid < NCLUST) scs[tid] = csq[tid];

    f32x4 acc[8];
    #pragma unroll
    for (int nr = 0; nr < 8; ++nr) acc[nr] = (f32x4){0.f, 0.f, 0.f, 0.f};

    __syncthreads();   // vmcnt(0): B half0 + A slots 0..3 resident
    __builtin_amdgcn_sched_barrier(0);

    #define KSTEP(ks, sl)                                                    \
    do {                                                                     \
        /* consume slot: split2 -> f16 fragments (data drained by barrier)*/ \
        f16x8 ah, am;                                                        \
        _Pragma("unroll")                                                    \
        for (int e = 0; e < 8; ++e) {                                        \
            float xe = ax[(ks) & 3][e >> 2][e & 3];                          \
            f16_t h, m;                                                      \
            split2(xe, h, m);                                                \
            ah[e] = h; am[e] = m;                                            \
        }                                                                    \
        _Pragma("unroll")                                                    \
        for (int nr = 0; nr < 8; ++nr) {                                     \
            int n = nr * 16 + lr;                                            \
            const char* bb = (const char*)Bs + (sl) * 16384 + n * 128;       \
            f16x8 bh = *(const f16x8*)(bb + (((lg    ) ^ (n & 7)) << 4));    \
            f16x8 bm = *(const f16x8*)(bb + (((4 + lg) ^ (n & 7)) << 4));    \
            f32x4 c4 = acc[nr];                                              \
            c4 = __builtin_amdgcn_mfma_f32_16x16x32_f16(am, bh, c4, 0, 0, 0);\
            c4 = __builtin_amdgcn_mfma_f32_16x16x32_f16(ah, bm, c4, 0, 0, 0);\
            c4 = __builtin_amdgcn_mfma_f32_16x16x32_f16(ah, bh, c4, 0, 0, 0);\
            acc[nr] = c4;                                                    \
        }                                                                    \
    } while (0)

    // ---- K half 0 (ks 0..3), all slots barrier-drained ----
    KSTEP(0, 0);
    KSTEP(1, 1);
    KSTEP(2, 2);
    KSTEP(3, 3);

    __syncthreads();   // all waves done reading Bs half0
    STAGE(1);          // overwrite Bs with K-half 1 (L2-hot, 64 KB)
    AISSUE(0, 4);      // re-arm the ring for half 1
    AISSUE(1, 5);
    AISSUE(2, 6);
    AISSUE(3, 7);
    __syncthreads();   // vmcnt(0): B half1 + A slots resident
    __builtin_amdgcn_sched_barrier(0);

    // ---- K half 1 (ks 4..7) ----
    KSTEP(4, 0);
    KSTEP(5, 1);
    KSTEP(6, 2);
    KSTEP(7, 3);
    #undef KSTEP
    #undef AISSUE
    #undef STAGE

    // ---- wave-local argmin + EPS count (wave owns ALL 128 clusters) ----
    // C layout: col(cluster) = lr (+nr*16), row(token) = lg*4 + reg
    #pragma unroll
    for (int reg = 0; reg < 4; ++reg) {
        float bv = INFINITY;
        int bi = 0;
        #pragma unroll
        for (int nr = 0; nr < 8; ++nr) {
            float v = fmaf(-2.f, acc[nr][reg], scs[nr * 16 + lr]);
            int c = nr * 16 + lr;
            if (v < bv) { bv = v; bi = c; }
        }
        #pragma unroll
        for (int msk = 1; msk < 16; msk <<= 1) {
            float ov = __shfl_xor(bv, msk, 64);
            int oi = __shfl_xor(bi, msk, 64);
            if (ov < bv || (ov == bv && oi < bi)) { bv = ov; bi = oi; }
        }
        float thr = bv + EPS;
        int cnt = 0;
        #pragma unroll
        for (int nr = 0; nr < 8; ++nr) {
            float v = fmaf(-2.f, acc[nr][reg], scs[nr * 16 + lr]);
            cnt += (v <= thr) ? 1 : 0;
        }
        #pragma unroll
        for (int msk = 1; msk < 16; msk <<= 1)
            cnt += __shfl_xor(cnt, msk, 64);
        if (lr == 0) {
            sbest[wid][lg * 4 + reg] = bi;
            scnt[wid][lg * 4 + reg] = cnt;
        }
    }
    asm volatile("s_waitcnt lgkmcnt(0)" ::: "memory");   // wave-local LDS visible
    __builtin_amdgcn_sched_barrier(0);

    // ---- exact fp32 recheck for near-tie tokens (rare, wave-local) ----
    // Bitwise round-1 arithmetic: sequential-k fmaf dot & xsq,
    // d2 = fmaf(-2,dot,xsq) + csq, lexicographic (value,idx) min.
    for (int tt = 0; tt < 16; ++tt) {
        if (scnt[wid][tt] < 2) continue;   // wave-uniform (broadcast read)
        const float4* xr = (const float4*)(x + (size_t)(tw + tt) * DIM);
        const float4* c0 = (const float4*)(centers + (size_t)(2 * lane) * DIM);
        const float4* c1 = (const float4*)(centers + (size_t)(2 * lane + 1) * DIM);
        float xs = 0.f, d0 = 0.f, d1 = 0.f;
        #pragma unroll 4
        for (int k4 = 0; k4 < 64; ++k4) {
            float4 xv = xr[k4];
            float4 a = c0[k4];
            float4 b = c1[k4];
            xs = fmaf(xv.x, xv.x, xs); d0 = fmaf(xv.x, a.x, d0); d1 = fmaf(xv.x, b.x, d1);
            xs = fmaf(xv.y, xv.y, xs); d0 = fmaf(xv.y, a.y, d0); d1 = fmaf(xv.y, b.y, d1);
            xs = fmaf(xv.z, xv.z, xs); d0 = fmaf(xv.z, a.z, d0); d1 = fmaf(xv.z, b.z, d1);
            xs = fmaf(xv.w, xv.w, xs); d0 = fmaf(xv.w, a.w, d0); d1 = fmaf(xv.w, b.w, d1);
        }
        float s0 = fmaf(-2.f, d0, xs) + csq[2 * lane];
        float s1 = fmaf(-2.f, d1, xs) + csq[2 * lane + 1];
        float bv = s0;
        int bi = 2 * lane;
        if (s1 < bv) { bv = s1; bi = 2 * lane + 1; }
        #pragma unroll
        for (int msk = 1; msk < 64; msk <<= 1) {
            float ov = __shfl_xor(bv, msk, 64);
            int oi = __shfl_xor(bi, msk, 64);
            if (ov < bv || (ov == bv && oi < bi)) { bv = ov; bi = oi; }
        }
        if (lane == 0) sbest[wid][tt] = bi;
    }
    asm volatile("s_waitcnt lgkmcnt(0)" ::: "memory");
    __builtin_amdgcn_sched_barrier(0);

    // ---- write this wave's 16 best indices ----
    if (lane < 16) best_out[tw + lane] = sbest[wid][lane];
}

// ---------------- kernel 3: streaming gather epilogue (unchanged) -------
__global__ __launch_bounds__(256) void epilogue_kernel(
    const int* __restrict__ best,
    const unsigned char* __restrict__ masks,
    const float* __restrict__ pc,
    float* __restrict__ out)
{
    const int idx0 = blockIdx.x * 256 + threadIdx.x;   // float4 index
    int   bst[8];
    float mv[8];
    #pragma unroll
    for (int it = 0; it < 8; ++it) {
        int t = (idx0 + it * 524288) >> 6;
        bst[it] = best[t];
        mv[it] = masks[t] ? 0.f : 1.f;
    }
    #pragma unroll
    for (int it = 0; it < 8; ++it) {
        int idx = idx0 + it * 524288;
        int f = idx & 63;
        float4 v = *(const float4*)(pc + (size_t)bst[it] * DOUT + f * 4);
        v.x *= mv[it]; v.y *= mv[it]; v.z *= mv[it]; v.w *= mv[it];
        *(float4*)(out + (size_t)idx * 4) = v;
    }
}

extern "C" void kernel_launch(void* const* d_in, const int* in_sizes, int n_in,
                              void* d_out, int out_size, void* d_ws, size_t ws_size,
                              hipStream_t stream) {
    const float* x = (const float*)d_in[0];
    const float* centers = (const float*)d_in[1];
    const float* proj_w = (const float*)d_in[2];
    const float* proj_b = (const float*)d_in[3];
    const unsigned char* masks = (const unsigned char*)d_in[4];
    float* out = (float*)d_out;

    char* ws = (char*)d_ws;
    float* pc    = (float*)(ws);                // 131072 B
    float* csq   = (float*)(ws + 131072);       // 512 B
    f16_t* cbs   = (f16_t*)(ws + 131584);       // 131072 B
    int*   bestw = (int*)(ws + 262656);         // 262144 B

    precompute_kernel<<<NCLUST, 256, 0, stream>>>(centers, proj_w, proj_b,
                                                  pc, csq, cbs);
    cluster_mfma_kernel<<<N_TOKENS / 256, 1024, 0, stream>>>(x, centers, cbs,
                                                             csq, bestw);
    epilogue_kernel<<<2048, 256, 0, stream>>>(bestw, masks, pc, out);
}

// Round 19
// 54.956 us; speedup vs baseline: 1.0812x; 1.0812x over previous
//
#include <hip/hip_runtime.h>
#include <cmath>

#define N_TOKENS 65536
#define DIM 256
#define NCLUST 128
#define DOUT 256

#define EPS 2e-3f

typedef _Float16 f16_t;
typedef f16_t f16x8 __attribute__((ext_vector_type(8)));
typedef float f32x4 __attribute__((ext_vector_type(4)));
typedef float fvec4 __attribute__((ext_vector_type(4)));

__device__ inline void split2(float x, f16_t& h, f16_t& m) {
    h = (f16_t)x;
    float r = x - (float)h;   // exact (Sterbenz)
    m = (f16_t)r;             // dropped residual ~2^-22 relative
}

__device__ inline void lds_load16(void* lds, const void* g) {
    __builtin_amdgcn_global_load_lds(
        (const __attribute__((address_space(1))) unsigned int*)g,
        (__attribute__((address_space(3))) unsigned int*)lds, 16, 0, 0);
}

// ---------------- kernel 1: precompute (unchanged, 11x-passing) ---------
__global__ __launch_bounds__(256) void precompute_kernel(
    const float* __restrict__ centers,
    const float* __restrict__ proj_w,
    const float* __restrict__ proj_b,
    float* __restrict__ pc,
    float* __restrict__ csq,
    f16_t* __restrict__ cbs)
{
    __shared__ float cl[DIM];
    __shared__ float red[4];
    const int n = blockIdx.x;
    const int tid = threadIdx.x;

    float cv = centers[n * DIM + tid];
    cl[tid] = cv;

    f16_t h, m;
    split2(cv, h, m);
    {
        int s  = tid >> 5;
        int k8 = (tid >> 3) & 3;
        int j  = tid & 7;
        size_t base = (size_t)(s * 128 + n) * 8;
        cbs[(base + ((k8    ) ^ (n & 7))) * 8 + j] = h;   // plane 0 (high)
        cbs[(base + ((4 + k8) ^ (n & 7))) * 8 + j] = m;   // plane 1 (mid)
    }

    float s = cv * cv;
    #pragma unroll
    for (int off = 32; off >= 1; off >>= 1)
        s += __shfl_down(s, off, 64);
    if ((tid & 63) == 0) red[tid >> 6] = s;
    __syncthreads();
    if (tid == 0) csq[n] = (red[0] + red[1]) + (red[2] + red[3]);

    float acc = 0.f;
    const float* wrow = proj_w + (size_t)tid * DIM;
    #pragma unroll 4
    for (int d = 0; d < DIM; d += 4) {
        float4 w = *(const float4*)(wrow + d);
        acc = fmaf(w.x, cl[d + 0], acc);
        acc = fmaf(w.y, cl[d + 1], acc);
        acc = fmaf(w.z, cl[d + 2], acc);
        acc = fmaf(w.w, cl[d + 3], acc);
    }
    pc[(size_t)n * DOUT + tid] = acc + proj_b[tid];
}

// -------- kernel 2: r12 base + asm-batched ds_read_b128 B-reads ---------
__global__ __launch_bounds__(1024, 4) void cluster_mfma_kernel(
    const float* __restrict__ x,
    const float* __restrict__ centers,
    const f16_t* __restrict__ cbs,
    const float* __restrict__ csq,
    int* __restrict__ best_out)
{
    __shared__ f16_t Bs[NCLUST * DIM * 2];   // 131072 B: whole split-B image
    __shared__ float scs[NCLUST];
    __shared__ int sbest[16][16];
    __shared__ int scnt[16][16];

    const int tid = threadIdx.x;
    const int lane = tid & 63;
    const int wid = tid >> 6;               // 0..15
    const int lr = lane & 15;
    const int lg = lane >> 4;
    const int tw = blockIdx.x * 256 + wid * 16;   // this wave's 16 tokens

    // ---- stage ENTIRE B once (linear copy of the pre-swizzled image) ----
    #pragma unroll
    for (int it = 0; it < 8; ++it) {
        int o = it * 1024 + tid;
        lds_load16((char*)Bs + o * 16, (const char*)cbs + o * 16);
    }
    if (tid < NCLUST) scs[tid] = csq[tid];

    __syncthreads();   // drains vmcnt(0): B resident, clean vm counter.
    __builtin_amdgcn_sched_barrier(0);

    f32x4 acc[8];
    #pragma unroll
    for (int nr = 0; nr < 8; ++nr) acc[nr] = (f32x4){0.f, 0.f, 0.f, 0.f};

    // A: token = tw + lr, k = ks*32 + lg*8 + j  (fp32 from global)
    const float* abase = x + (size_t)(tw + lr) * DIM + lg * 8;

    // depth-4 ASM ring: 2 dwordx4 per slot, 8 loads in flight per lane.
    fvec4 ax[4][2];
    #define AISSUE(slot, ksv) do {                                           \
        asm volatile("global_load_dwordx4 %0, %1, off offset:%c2"            \
                     : "=&v"(ax[slot][0]) : "v"(abase), "i"((ksv) * 128)     \
                     : "memory");                                            \
        asm volatile("global_load_dwordx4 %0, %1, off offset:%c2"            \
                     : "=&v"(ax[slot][1]) : "v"(abase), "i"((ksv) * 128 + 16)\
                     : "memory");                                            \
    } while (0)

    AISSUE(0, 0);
    AISSUE(1, 1);
    AISSUE(2, 2);
    AISSUE(3, 3);

    // lane-constant LDS byte offsets for the two swizzled B planes
    const unsigned bbase =
        (unsigned)(uintptr_t)(__attribute__((address_space(3))) char*)Bs;
    const unsigned lo1 = bbase + lr * 128 + ((lg ^ (lr & 7)) << 4);
    const unsigned lo2 = bbase + lr * 128 + (((4 + lg) ^ (lr & 7)) << 4);

    #pragma unroll
    for (int ks = 0; ks < 8; ++ks) {
        const int cur = ks & 3;
        // in-order vmcnt: slot cur's 2 loads retired at these counts
        if (ks <= 4)      asm volatile("s_waitcnt vmcnt(6)" ::: "memory");
        else if (ks == 5) asm volatile("s_waitcnt vmcnt(4)" ::: "memory");
        else if (ks == 6) asm volatile("s_waitcnt vmcnt(2)" ::: "memory");
        else              asm volatile("s_waitcnt vmcnt(0)" ::: "memory");
        __builtin_amdgcn_sched_barrier(0);   // rule #18: pin consumers below

        // consume slot cur: split2 -> f16 fragments
        f16x8 ah, am;
        #pragma unroll
        for (int e = 0; e < 8; ++e) {
            float xe = ax[cur][e >> 2][e & 3];
            f16_t h, m;
            split2(xe, h, m);
            ah[e] = h; am[e] = m;
        }
        // refill the just-freed slot
        if (ks < 4) AISSUE(cur, ks + 4);

        const unsigned av1 = lo1 + ks * 16384;
        const unsigned av2 = lo2 + ks * 16384;

        // B in two nr-half batches: 8 asm ds_read_b128 issued back-to-back
        // (cannot be split/sunk), lgkmcnt(0) + fence, then 12 MFMAs.
        #pragma unroll
        for (int nh = 0; nh < 2; ++nh) {
            f16x8 bf[4][2];
            #pragma unroll
            for (int q = 0; q < 4; ++q) {
                asm volatile("ds_read_b128 %0, %1 offset:%c2"
                             : "=&v"(bf[q][0])
                             : "v"(av1), "i"((nh * 4 + q) * 2048));
                asm volatile("ds_read_b128 %0, %1 offset:%c2"
                             : "=&v"(bf[q][1])
                             : "v"(av2), "i"((nh * 4 + q) * 2048));
            }
            asm volatile("s_waitcnt lgkmcnt(0)" ::: "memory");
            __builtin_amdgcn_sched_barrier(0);
            #pragma unroll
            for (int q = 0; q < 4; ++q) {
                int nr = nh * 4 + q;
                f32x4 c4 = acc[nr];
                c4 = __builtin_amdgcn_mfma_f32_16x16x32_f16(am, bf[q][0], c4, 0, 0, 0);
                c4 = __builtin_amdgcn_mfma_f32_16x16x32_f16(ah, bf[q][1], c4, 0, 0, 0);
                c4 = __builtin_amdgcn_mfma_f32_16x16x32_f16(ah, bf[q][0], c4, 0, 0, 0);
                acc[nr] = c4;
            }
        }
        __builtin_amdgcn_sched_barrier(0);
    }
    #undef AISSUE

    // ---- wave-local argmin + EPS count (wave owns ALL 128 clusters) ----
    // C layout: col(cluster) = lr (+nr*16), row(token) = lg*4 + reg
    #pragma unroll
    for (int reg = 0; reg < 4; ++reg) {
        float bv = INFINITY;
        int bi = 0;
        #pragma unroll
        for (int nr = 0; nr < 8; ++nr) {
            float v = fmaf(-2.f, acc[nr][reg], scs[nr * 16 + lr]);
            int c = nr * 16 + lr;
            if (v < bv) { bv = v; bi = c; }
        }
        #pragma unroll
        for (int msk = 1; msk < 16; msk <<= 1) {
            float ov = __shfl_xor(bv, msk, 64);
            int oi = __shfl_xor(bi, msk, 64);
            if (ov < bv || (ov == bv && oi < bi)) { bv = ov; bi = oi; }
        }
        float thr = bv + EPS;
        int cnt = 0;
        #pragma unroll
        for (int nr = 0; nr < 8; ++nr) {
            float v = fmaf(-2.f, acc[nr][reg], scs[nr * 16 + lr]);
            cnt += (v <= thr) ? 1 : 0;
        }
        #pragma unroll
        for (int msk = 1; msk < 16; msk <<= 1)
            cnt += __shfl_xor(cnt, msk, 64);
        if (lr == 0) {
            sbest[wid][lg * 4 + reg] = bi;
            scnt[wid][lg * 4 + reg] = cnt;
        }
    }
    asm volatile("s_waitcnt lgkmcnt(0)" ::: "memory");   // wave-local LDS visible
    __builtin_amdgcn_sched_barrier(0);

    // ---- exact fp32 recheck for near-tie tokens (rare, wave-local) ----
    // Bitwise round-1 arithmetic: sequential-k fmaf dot & xsq,
    // d2 = fmaf(-2,dot,xsq) + csq, lexicographic (value,idx) min.
    for (int tt = 0; tt < 16; ++tt) {
        if (scnt[wid][tt] < 2) continue;   // wave-uniform (broadcast read)
        const float4* xr = (const float4*)(x + (size_t)(tw + tt) * DIM);
        const float4* c0 = (const float4*)(centers + (size_t)(2 * lane) * DIM);
        const float4* c1 = (const float4*)(centers + (size_t)(2 * lane + 1) * DIM);
        float xs = 0.f, d0 = 0.f, d1 = 0.f;
        #pragma unroll 4
        for (int k4 = 0; k4 < 64; ++k4) {
            float4 xv = xr[k4];
            float4 a = c0[k4];
            float4 b = c1[k4];
            xs = fmaf(xv.x, xv.x, xs); d0 = fmaf(xv.x, a.x, d0); d1 = fmaf(xv.x, b.x, d1);
            xs = fmaf(xv.y, xv.y, xs); d0 = fmaf(xv.y, a.y, d0); d1 = fmaf(xv.y, b.y, d1);
            xs = fmaf(xv.z, xv.z, xs); d0 = fmaf(xv.z, a.z, d0); d1 = fmaf(xv.z, b.z, d1);
            xs = fmaf(xv.w, xv.w, xs); d0 = fmaf(xv.w, a.w, d0); d1 = fmaf(xv.w, b.w, d1);
        }
        float s0 = fmaf(-2.f, d0, xs) + csq[2 * lane];
        float s1 = fmaf(-2.f, d1, xs) + csq[2 * lane + 1];
        float bv = s0;
        int bi = 2 * lane;
        if (s1 < bv) { bv = s1; bi = 2 * lane + 1; }
        #pragma unroll
        for (int msk = 1; msk < 64; msk <<= 1) {
            float ov = __shfl_xor(bv, msk, 64);
            int oi = __shfl_xor(bi, msk, 64);
            if (ov < bv || (ov == bv && oi < bi)) { bv = ov; bi = oi; }
        }
        if (lane == 0) sbest[wid][tt] = bi;
    }
    asm volatile("s_waitcnt lgkmcnt(0)" ::: "memory");
    __builtin_amdgcn_sched_barrier(0);

    // ---- write this wave's 16 best indices ----
    if (lane < 16) best_out[tw + lane] = sbest[wid][lane];
}

// ---------------- kernel 3: streaming gather epilogue (unchanged) -------
__global__ __launch_bounds__(256) void epilogue_kernel(
    const int* __restrict__ best,
    const unsigned char* __restrict__ masks,
    const float* __restrict__ pc,
    float* __restrict__ out)
{
    const int idx0 = blockIdx.x * 256 + threadIdx.x;   // float4 index
    int   bst[8];
    float mv[8];
    #pragma unroll
    for (int it = 0; it < 8; ++it) {
        int t = (idx0 + it * 524288) >> 6;
        bst[it] = best[t];
        mv[it] = masks[t] ? 0.f : 1.f;
    }
    #pragma unroll
    for (int it = 0; it < 8; ++it) {
        int idx = idx0 + it * 524288;
        int f = idx & 63;
        float4 v = *(const float4*)(pc + (size_t)bst[it] * DOUT + f * 4);
        v.x *= mv[it]; v.y *= mv[it]; v.z *= mv[it]; v.w *= mv[it];
        *(float4*)(out + (size_t)idx * 4) = v;
    }
}

extern "C" void kernel_launch(void* const* d_in, const int* in_sizes, int n_in,
                              void* d_out, int out_size, void* d_ws, size_t ws_size,
                              hipStream_t stream) {
    const float* x = (const float*)d_in[0];
    const float* centers = (const float*)d_in[1];
    const float* proj_w = (const float*)d_in[2];
    const float* proj_b = (const float*)d_in[3];
    const unsigned char* masks = (const unsigned char*)d_in[4];
    float* out = (float*)d_out;

    char* ws = (char*)d_ws;
    float* pc    = (float*)(ws);                // 131072 B
    float* csq   = (float*)(ws + 131072);       // 512 B
    f16_t* cbs   = (f16_t*)(ws + 131584);       // 131072 B
    int*   bestw = (int*)(ws + 262656);         // 262144 B

    precompute_kernel<<<NCLUST, 256, 0, stream>>>(centers, proj_w, proj_b,
                                                  pc, csq, cbs);
    cluster_mfma_kernel<<<N_TOKENS / 256, 1024, 0, stream>>>(x, centers, cbs,
                                                             csq, bestw);
    epilogue_kernel<<<2048, 256, 0, stream>>>(bestw, masks, pc, out);
}